// Round 1
// 63.432 us; speedup vs baseline: 1.0048x; 1.0048x over previous
//
#include <hip/hip_runtime.h>

// Problem constants (fixed by setup_inputs)
#define M_PTS   1024
#define B_SZ    2
#define NC      64
#define KS      13
#define NA      20
#define DIM_OUT 64

#define NBLK_PER_C 5                 // a-slices per center
#define A_SLICE    4                 // NA / NBLK_PER_C
#define NITEMS     (KS * A_SLICE)    // 52 (k,a) items per block
#define NWAVES     8                 // RBF waves (point split 8 ways)
#define CWAVES     4                 // compaction waves (4 pts/lane each, as before)
#define NTHREADS   (NWAVES * 64)     // 512

static constexpr float R2    = 0.4f * 0.4f;                          // 0.16
static constexpr float C2SIG = 6.25f * 1.44269504088896340736f;      // (1/(2*sigma)) * log2(e)

__global__ __launch_bounds__(NTHREADS)
void KernelPropagation_24206435681031_kernel(const float* __restrict__ frag,    // (M,3)
                                             const float* __restrict__ clouds,  // (B,3,NC)
                                             const float* __restrict__ kernels, // (KS,NA,3)
                                             const float* __restrict__ W,       // (DIM_OUT,KS)
                                             float* __restrict__ out)           // (B,DIM_OUT,NC,NA)
{
    const int g    = blockIdx.x;             // 0..B*NC*NBLK_PER_C-1
    const int bc   = g / NBLK_PER_C;         // center 0..127
    const int sl   = g % NBLK_PER_C;         // a-slice 0..4
    const int b    = bc / NC;
    const int n    = bc % NC;
    const int t    = threadIdx.x;
    const int lane = t & 63;
    const int w    = t >> 6;                 // wave id 0..7

    __shared__ float4 pf[M_PTS];             // compacted points: (x, y, z, -C*|p|^2)
    __shared__ float  part[NWAVES * NITEMS]; // per-eighth partial sums
    __shared__ float  accs[NITEMS];
    __shared__ int    wtot[CWAVES];          // per-compaction-wave in-ball totals

    const float cx = clouds[(b * 3 + 0) * NC + n];
    const float cy = clouds[(b * 3 + 1) * NC + n];
    const float cz = clouds[(b * 3 + 2) * NC + n];

    // ---- Compaction front-end: waves 0..3 own points [w*256, w*256+256).
    // Lane l holds 4 points via 3 coalesced float4 loads (issued up-front,
    // no serial dependency). frag is (1024,3) floats = 768 float4s.
    float4 va = make_float4(0.f, 0.f, 0.f, 0.f);
    float4 vb = va, vc = va;
    if (w < CWAVES) {
        const float4* fragv = (const float4*)frag;
        const int fb = w * 192 + 3 * lane;
        va = fragv[fb + 0];
        vb = fragv[fb + 1];
        vc = fragv[fb + 2];
    }

    // ---- Hide the load latency: per-lane rotated kernel point + prescale.
    //   wgt = exp2( -C|p|^2 + 2C*(p.k) - C|k|^2 ) = exp2( p.w + dot(p.xyz,k2) ) * ek
    const int  item   = lane;
    const bool active = item < NITEMS;
    float kx2 = 0.f, ky2 = 0.f, kz2 = 0.f, ek = 0.f;
    if (active) {
        const int k  = item >> 2;
        const int a  = sl * A_SLICE + (item & 3);
        const int ki = (k * NA + a) * 3;
        const float kx = cx + kernels[ki + 0];
        const float ky = cy + kernels[ki + 1];
        const float kz = cz + kernels[ki + 2];
        ek  = exp2f(-C2SIG * (kx * kx + ky * ky + kz * kz));
        kx2 = (2.0f * C2SIG) * kx;
        ky2 = (2.0f * C2SIG) * ky;
        kz2 = (2.0f * C2SIG) * kz;
    }

    // ---- Ball test on 4 points, 4 ballots, register prefix (no atomics).
    if (w < CWAVES) {
        const float x0 = va.x, y0 = va.y, z0 = va.z;
        const float x1 = va.w, y1 = vb.x, z1 = vb.y;
        const float x2 = vb.z, y2 = vb.w, z2 = vc.x;
        const float x3 = vc.y, y3 = vc.z, z3 = vc.w;

        const float dx0 = x0 - cx, dy0 = y0 - cy, dz0 = z0 - cz;
        const float dx1 = x1 - cx, dy1 = y1 - cy, dz1 = z1 - cz;
        const float dx2 = x2 - cx, dy2 = y2 - cy, dz2 = z2 - cz;
        const float dx3 = x3 - cx, dy3 = y3 - cy, dz3 = z3 - cz;

        const bool in0 = (dx0 * dx0 + dy0 * dy0 + dz0 * dz0) < R2;
        const bool in1 = (dx1 * dx1 + dy1 * dy1 + dz1 * dz1) < R2;
        const bool in2 = (dx2 * dx2 + dy2 * dy2 + dz2 * dz2) < R2;
        const bool in3 = (dx3 * dx3 + dy3 * dy3 + dz3 * dz3) < R2;

        const unsigned long long m0 = __ballot(in0);
        const unsigned long long m1 = __ballot(in1);
        const unsigned long long m2 = __ballot(in2);
        const unsigned long long m3 = __ballot(in3);

        const int c0 = __popcll(m0), c1 = __popcll(m1), c2 = __popcll(m2);
        if (lane == 0) wtot[w] = c0 + c1 + c2 + __popcll(m3);
        __syncthreads();

        int base = 0;
        if (w > 0) base += wtot[0];
        if (w > 1) base += wtot[1];
        if (w > 2) base += wtot[2];

        const unsigned long long below = (1ull << lane) - 1ull;
        if (in0) pf[base + __popcll(m0 & below)]
                     = make_float4(x0, y0, z0, -C2SIG * (x0 * x0 + y0 * y0 + z0 * z0));
        if (in1) pf[base + c0 + __popcll(m1 & below)]
                     = make_float4(x1, y1, z1, -C2SIG * (x1 * x1 + y1 * y1 + z1 * z1));
        if (in2) pf[base + c0 + c1 + __popcll(m2 & below)]
                     = make_float4(x2, y2, z2, -C2SIG * (x2 * x2 + y2 * y2 + z2 * z2));
        if (in3) pf[base + c0 + c1 + c2 + __popcll(m3 & below)]
                     = make_float4(x3, y3, z3, -C2SIG * (x3 * x3 + y3 * y3 + z3 * z3));
    } else {
        __syncthreads();                     // pair with the wtot barrier above
    }
    __syncthreads();

    const int npts = wtot[0] + wtot[1] + wtot[2] + wtot[3];
    const float inv = 1.0f / ((float)npts + 1.0f);

    // ---- RBF: item = lane (<52), point-eighth = wave id; broadcast LDS reads.
    const int jlo = (npts * w)       >> 3;
    const int jhi = (npts * (w + 1)) >> 3;

    float s0 = 0.f, s1 = 0.f;
    int j = jlo;
    for (; j + 3 < jhi; j += 4) {
        const float4 p0 = pf[j + 0];
        const float4 p1 = pf[j + 1];
        const float4 p2 = pf[j + 2];
        const float4 p3 = pf[j + 3];
        float u0 = fmaf(p0.z, kz2, fmaf(p0.y, ky2, p0.x * kx2)) + p0.w;
        float u1 = fmaf(p1.z, kz2, fmaf(p1.y, ky2, p1.x * kx2)) + p1.w;
        float u2 = fmaf(p2.z, kz2, fmaf(p2.y, ky2, p2.x * kx2)) + p2.w;
        float u3 = fmaf(p3.z, kz2, fmaf(p3.y, ky2, p3.x * kx2)) + p3.w;
        s0 = fmaf(ek, exp2f(u0), s0);
        s1 = fmaf(ek, exp2f(u1), s1);
        s0 = fmaf(ek, exp2f(u2), s0);
        s1 = fmaf(ek, exp2f(u3), s1);
    }
    for (; j < jhi; ++j) {
        const float4 p0 = pf[j];
        float u0 = fmaf(p0.z, kz2, fmaf(p0.y, ky2, p0.x * kx2)) + p0.w;
        s0 = fmaf(ek, exp2f(u0), s0);
    }
    if (active) part[w * NITEMS + item] = s0 + s1;
    __syncthreads();

    // ---- Reduce eighths, normalize
    if (t < NITEMS) {
        float s = part[t];
#pragma unroll
        for (int i = 1; i < NWAVES; ++i) s += part[i * NITEMS + t];
        accs[t] = s * inv;                  // accs[k*4 + jj], jj -> a = sl*4 + jj
    }
    __syncthreads();

    // ---- Epilogue: 256 outputs for this slice, one per thread (waves 0..3).
    //      o = t>>2, jj = t&3:  out[b,o,n,sl*4+jj] = sum_k W[o,k]*accs[k*4+jj]
    if (t < DIM_OUT * A_SLICE) {
        const int o  = t >> 2;
        const int jj = t & 3;
        float f = 0.f;
#pragma unroll
        for (int k = 0; k < KS; ++k)
            f = fmaf(W[o * KS + k], accs[k * 4 + jj], f);
        out[((size_t)(b * DIM_OUT + o) * NC + n) * NA + sl * A_SLICE + jj] = f;
    }
}

extern "C" void kernel_launch(void* const* d_in, const int* in_sizes, int n_in,
                              void* d_out, int out_size, void* d_ws, size_t ws_size,
                              hipStream_t stream) {
    const float* frag    = (const float*)d_in[0];   // (1024,3)
    const float* clouds  = (const float*)d_in[1];   // (2,3,64)
    const float* kernels = (const float*)d_in[2];   // (13,20,3)
    const float* W       = (const float*)d_in[3];   // (64,13)
    float* out = (float*)d_out;                     // (2,64,64,20)

    (void)in_sizes; (void)n_in; (void)out_size; (void)d_ws; (void)ws_size;

    KernelPropagation_24206435681031_kernel<<<B_SZ * NC * NBLK_PER_C, NTHREADS, 0, stream>>>(
        frag, clouds, kernels, W, out);
}